// Round 6
// baseline (450.173 us; speedup 1.0000x reference)
//
#include <hip/hip_runtime.h>
#include <stdint.h>

typedef uint32_t u32;
typedef uint64_t u64;

#define KREN 1000
#define NBLK 256
#define NTHR 1024
#define TOT (NBLK * NTHR)
#define CAND0_CAP 16384
#define CAND_CAP 4096
#define GSTRIDE 12
#define SEGN 16   // render: gaussian segments per pixel
#define PXT 4     // pixels per thread

// monotonic float -> u32 key (larger key == larger float)
__device__ __forceinline__ u32 fkey(float f) {
  u32 b = __float_as_uint(f);
  return (b & 0x80000000u) ? ~b : (b | 0x80000000u);
}

// Grid barrier: RELAXED spin, RELEASE arrive, one ACQUIRE fence on wakeup.
__device__ __forceinline__ void grid_sync(u32* bar) {
  __syncthreads();
  if (threadIdx.x == 0) {
    u32 gen = __hip_atomic_load(&bar[1], __ATOMIC_RELAXED, __HIP_MEMORY_SCOPE_AGENT);
    u32 arr = __hip_atomic_fetch_add(&bar[0], 1u, __ATOMIC_RELEASE, __HIP_MEMORY_SCOPE_AGENT);
    if (arr == NBLK - 1) {
      __hip_atomic_store(&bar[0], 0u, __ATOMIC_RELAXED, __HIP_MEMORY_SCOPE_AGENT);
      __hip_atomic_store(&bar[1], gen + 1u, __ATOMIC_RELEASE, __HIP_MEMORY_SCOPE_AGENT);
    } else {
      while (__hip_atomic_load(&bar[1], __ATOMIC_RELAXED, __HIP_MEMORY_SCOPE_AGENT) == gen)
        __builtin_amdgcn_s_sleep(4);
    }
    __builtin_amdgcn_fence(__ATOMIC_ACQUIRE, "agent");
  }
  __syncthreads();
}

// Block-redundant pick over 4096-bin global hist: bin where descending
// cumulative count first reaches K. Deterministic across blocks.
__device__ __forceinline__ void pick_scan(const u32* __restrict__ hist, u32 K,
                                          u32* lds, int* bin_out, u32* Krem_out) {
  int tid = threadIdx.x;
  u32 hv[4];
  u32 s = 0;
#pragma unroll
  for (int k = 0; k < 4; ++k) { hv[k] = hist[tid * 4 + k]; s += hv[k]; }
  lds[tid] = s;
  __syncthreads();
  for (int d = 1; d < NTHR; d <<= 1) {  // inclusive suffix sum
    u32 v = lds[tid] + ((tid + d < NTHR) ? lds[tid + d] : 0u);
    __syncthreads();
    lds[tid] = v;
    __syncthreads();
  }
  u32 inc = lds[tid];
  u32 above = (tid < NTHR - 1) ? lds[tid + 1] : 0u;
  if (above < K && inc >= K) {
    u32 cum = above;
    for (int k = 3; k >= 0; --k) {
      cum += hv[k];
      if (cum >= K) {
        lds[NTHR] = (u32)(tid * 4 + k);
        lds[NTHR + 1] = K - (cum - hv[k]);
        break;
      }
    }
  }
  __syncthreads();
  *bin_out = (int)lds[NTHR];
  *Krem_out = lds[NTHR + 1];
  __syncthreads();
}

__global__ __launch_bounds__(NTHR) void k_fused(
    const float* __restrict__ pos, const float* __restrict__ scales,
    const float* __restrict__ rot, const float* __restrict__ colors,
    const float* __restrict__ opac, const float* __restrict__ csh,
    const float* __restrict__ cam, const float* __restrict__ campos,
    u32* __restrict__ keys, u64* __restrict__ cand0, u64* __restrict__ cand,
    float* __restrict__ gauss, u32* __restrict__ hist1, u32* __restrict__ hist2,
    u32* __restrict__ state, u32* __restrict__ bar, float* __restrict__ out,
    int N, int shstride) {
  __shared__ u64 smem[8192];  // 64 KB, phase-aliased
  u32* hl = (u32*)smem;
  int tid = threadIdx.x, bid = blockIdx.x;
  int gtid = bid * NTHR + tid;
  int lane = tid & 63;

  // ---------- P0: depth keys + 12-bit LDS hist (wave-aggregated) ----------
  for (int i = tid; i < 4096; i += NTHR) hl[i] = 0;
  __syncthreads();
  {
    float c8 = cam[8], c9 = cam[9], c10 = cam[10], c11 = cam[11];
    for (int i = gtid; i < N; i += TOT) {
      float x = pos[3 * i], y = pos[3 * i + 1], z = pos[3 * i + 2];
      u32 mk = fkey(c8 * x + c9 * y + c10 * z + c11);
      keys[i] = mk;
      u32 bin = mk >> 20;
      u64 todo = __ballot(true);
      while (todo) {
        int leader = __ffsll((unsigned long long)todo) - 1;
        u32 lbin = __shfl(bin, leader, 64);
        u64 same = __ballot(bin == lbin);
        if (lane == leader) atomicAdd(&hl[lbin], (u32)__popcll(same & todo));
        todo &= ~same;
      }
    }
  }
  __syncthreads();
  for (int i = tid; i < 4096; i += NTHR) {
    u32 v = hl[i];
    if (v) atomicAdd(&hist1[i], v);
  }
  grid_sync(bar);

  // ---------- P1: pick bin1 (redundant) + level-2 hist + compact emit ----------
  int bin1; u32 K1;
  pick_scan(hist1, (u32)KREN, hl, &bin1, &K1);
  u32 pref = (u32)bin1;
  for (int i = tid; i < 4096; i += NTHR) hl[i] = 0;
  __syncthreads();
  for (int i = gtid; i < N; i += TOT) {
    u32 k = keys[i];
    bool m = (k >> 20) == pref;
    if (m) atomicAdd(&hl[(k >> 8) & 4095u], 1u);
    u64 bm = __ballot(m);
    if (bm) {
      u32 base;
      int leader = __ffsll((unsigned long long)bm) - 1;
      if (lane == leader) base = atomicAdd(&state[1], (u32)__popcll(bm));
      base = __shfl(base, leader, 64);
      if (m) {
        u32 p = base + (u32)__popcll(bm & ((1ull << lane) - 1ull));
        if (p < CAND0_CAP) cand0[p] = (((u64)(~k)) << 32) | (u32)i;
      }
    }
  }
  __syncthreads();
  for (int i = tid; i < 4096; i += NTHR) {
    u32 v = hl[i];
    if (v) atomicAdd(&hist2[i], v);
  }
  grid_sync(bar);

  // ---------- P2: pick bin2 (redundant) + collect from compact buffer ----------
  int bin2; u32 K2;
  pick_scan(hist2, K1, hl, &bin2, &K2);
  {
    u32 Thi = ~((pref << 20) | (((u32)bin2) << 8));  // stored-key form: ~k <= Thi
    int M1 = (int)state[1];
    if (M1 > CAND0_CAP) M1 = CAND0_CAP;
    for (int i = gtid; i < M1; i += TOT) {
      u64 e = cand0[i];
      if ((u32)(e >> 32) <= Thi) {
        u32 p = atomicAdd(&state[0], 1u);
        if (p < CAND_CAP) cand[p] = e;
      }
    }
  }
  grid_sync(bar);

  // ---------- P3: rank (wave-per-candidate, all blocks) + prep ----------
  {
    u64* sc = smem;
    int M = (int)state[0];
    if (M > CAND_CAP) M = CAND_CAP;
    for (int i = tid; i < M; i += NTHR) sc[i] = cand[i];
    __syncthreads();
    int w = tid >> 6;
    int c = bid * 16 + w;
    if (c < M) {
      u64 mine = sc[c];
      int cnt = 0;
      int JJ = (M + 63) >> 6;
      for (int jj = 0; jj < JJ; ++jj) {
        int j = lane + (jj << 6);
        if (j < M && sc[j] < mine) ++cnt;
      }
#pragma unroll
      for (int d = 32; d; d >>= 1) cnt += __shfl_xor(cnt, d, 64);
      int r = cnt;
      if (r < KREN && lane == 0) {
        int g = (int)(u32)(mine & 0xffffffffu);
        float x = pos[3 * g], y = pos[3 * g + 1], z = pos[3 * g + 2];
        float c0 = cam[0], c1 = cam[1], c2 = cam[2], c3 = cam[3];
        float c4 = cam[4], c5 = cam[5], c6 = cam[6], c7 = cam[7];
        float c8 = cam[8], c9 = cam[9], c10 = cam[10], c11 = cam[11];
        float dep = c8 * x + c9 * y + c10 * z + c11;
        float invd = 1.0f / (dep + 1e-7f);
        float p2x = (c0 * x + c1 * y + c2 * z + c3) * invd;
        float p2y = (c4 * x + c5 * y + c6 * z + c7) * invd;
        float qw = rot[4 * g], qx = rot[4 * g + 1], qy = rot[4 * g + 2], qz = rot[4 * g + 3];
        float qn = rsqrtf(qw * qw + qx * qx + qy * qy + qz * qz);
        qw *= qn; qx *= qn; qy *= qn; qz *= qn;
        float r00 = 1.f - 2.f * (qy * qy + qz * qz), r01 = 2.f * (qx * qy - qw * qz), r02 = 2.f * (qx * qz + qw * qy);
        float r10 = 2.f * (qx * qy + qw * qz), r11 = 1.f - 2.f * (qx * qx + qz * qz), r12 = 2.f * (qy * qz - qw * qx);
        float r20 = 2.f * (qx * qz - qw * qy), r21 = 2.f * (qy * qz + qw * qx), r22 = 1.f - 2.f * (qx * qx + qy * qy);
        float e0 = fmaxf(expf(scales[3 * g]), 1e-7f);
        float e1 = fmaxf(expf(scales[3 * g + 1]), 1e-7f);
        float e2 = fmaxf(expf(scales[3 * g + 2]), 1e-7f);
        float v0 = e0 * e0, v1 = e1 * e1, v2 = e2 * e2;
        float C00 = r00 * r00 * v0 + r01 * r01 * v1 + r02 * r02 * v2;
        float C01 = r00 * r10 * v0 + r01 * r11 * v1 + r02 * r12 * v2;
        float C02 = r00 * r20 * v0 + r01 * r21 * v1 + r02 * r22 * v2;
        float C11 = r10 * r10 * v0 + r11 * r11 * v1 + r12 * r12 * v2;
        float C12 = r10 * r20 * v0 + r11 * r21 * v1 + r12 * r22 * v2;
        float C22 = r20 * r20 * v0 + r21 * r21 * v1 + r22 * r22 * v2;
        float fx = c0, fy = c5;
        float jd = 1.0f / dep;
        float j0 = fx * jd, j2 = -fx * p2x * jd, j4 = fy * jd, j5 = -fy * p2y * jd;
        float u0x = j0 * C00 + j2 * C02;
        float u0y = j0 * C01 + j2 * C12;
        float u0z = j0 * C02 + j2 * C22;
        float u1y = j4 * C11 + j5 * C12;
        float u1z = j4 * C12 + j5 * C22;
        float a = u0x * j0 + u0z * j2 + 1e-6f;
        float b = u0y * j4 + u0z * j5;
        float d2 = u1y * j4 + u1z * j5 + 1e-6f;
        float det = a * d2 - b * b;
        float idet = 1.0f / det;
        const float L = 1.4426950408889634f;
        float Aq = -0.5f * L * d2 * idet;
        float Bq = L * b * idet;
        float Cq = -0.5f * L * a * idet;
        float vx = x - campos[0], vy = y - campos[1], vz = z - campos[2];
        float vn = rsqrtf(vx * vx + vy * vy + vz * vz);
        vx *= vn; vy *= vn; vz *= vn;
        float sh[9];
        sh[0] = 0.28209479177387814f;
        sh[1] = -0.48860251190291987f * vy;
        sh[2] = 0.48860251190291987f * vz;
        sh[3] = -0.48860251190291987f * vx;
        sh[4] = 1.0925484305920792f * vx * vy;
        sh[5] = -1.0925484305920792f * vy * vz;
        sh[6] = 0.31539156525252005f * (2.f * vz * vz - vx * vx - vy * vy);
        sh[7] = -1.0925484305920792f * vx * vz;
        sh[8] = 0.5462742152960396f * (vx * vx - vy * vy);
        float col[3];
        for (int c2 = 0; c2 < 3; ++c2) {
          float accv = colors[3 * g + c2];
          for (int k2 = 0; k2 < 9; ++k2) accv += sh[k2] * csh[(size_t)g * shstride + 3 * k2 + c2];
          col[c2] = 1.0f / (1.0f + __expf(-accv));
        }
        float op = 1.0f / (1.0f + __expf(-opac[g]));
        float* G = gauss + r * GSTRIDE;
        G[0] = p2x; G[1] = p2y; G[2] = Aq; G[3] = Bq; G[4] = Cq;
        G[5] = op;  G[6] = col[0]; G[7] = col[1]; G[8] = col[2];
        G[9] = 0.f; G[10] = 0.f; G[11] = 0.f;
      }
    }
  }
  grid_sync(bar);

  // ---------- P4: render, 4 px/thread x 16 segments; comb aliases gs ----------
  {
    float* gs = (float*)smem;        // 12000 floats
    float4* g4s = (float4*)smem;
    const float4* g4 = (const float4*)gauss;
    for (int i = tid; i < 3000; i += NTHR) g4s[i] = g4[i];
    __syncthreads();
    int grp = tid & 63;              // pixel group: px0 = grp*4
    int seg = tid >> 6;              // 0..15
    float pxf = (float)(grp * 4);
    float pyf = (float)bid;          // block = image row
    float cr0 = 0.f, cr1 = 0.f, cr2 = 0.f, cr3 = 0.f;
    float cg0 = 0.f, cg1 = 0.f, cg2 = 0.f, cg3 = 0.f;
    float cb0 = 0.f, cb1 = 0.f, cb2 = 0.f, cb3 = 0.f;
    float ac0 = 0.f, ac1 = 0.f, ac2 = 0.f, ac3 = 0.f;
    int gbeg = (seg * KREN) / SEGN, gend = ((seg + 1) * KREN) / SEGN;
    for (int k = gbeg; k < gend; ++k) {
      const float4* Gp = (const float4*)(gs + k * GSTRIDE);
      float4 g0 = Gp[0];
      float4 g1 = Gp[1];
      float g2x = gs[k * GSTRIDE + 8];
      float A = g0.z, B = g0.w, C = g1.x, op = g1.y;
      float dx = pxf - g0.x, dy = pyf - g0.y;
      float q0 = (A * dx + B * dy) * dx + C * dy * dy;
      float u = 2.f * A * dx + B * dy;
      float q1 = q0 + u + A;
      float q2 = q0 + 2.f * u + 4.f * A;
      float q3 = q0 + 3.f * u + 9.f * A;
      float e0 = op * exp2f(q0), e1 = op * exp2f(q1);
      float e2 = op * exp2f(q2), e3 = op * exp2f(q3);
      float w0 = (1.f - ac0) * e0, w1 = (1.f - ac1) * e1;
      float w2 = (1.f - ac2) * e2, w3 = (1.f - ac3) * e3;
      cr0 += w0 * g1.z; cg0 += w0 * g1.w; cb0 += w0 * g2x; ac0 += w0;
      cr1 += w1 * g1.z; cg1 += w1 * g1.w; cb1 += w1 * g2x; ac1 += w1;
      cr2 += w2 * g1.z; cg2 += w2 * g1.w; cb2 += w2 * g2x; ac2 += w2;
      cr3 += w3 * g1.z; cg3 += w3 * g1.w; cb3 += w3 * g2x; ac3 += w3;
    }
    __syncthreads();  // all waves done reading gs; comb reuses smem
    float4* comb = (float4*)smem;    // [seg][px] -> 16*256 float4 = 64 KB
    int base = seg * 256 + grp * 4;
    comb[base + 0] = make_float4(cr0, cg0, cb0, 1.f - ac0);
    comb[base + 1] = make_float4(cr1, cg1, cb1, 1.f - ac1);
    comb[base + 2] = make_float4(cr2, cg2, cb2, 1.f - ac2);
    comb[base + 3] = make_float4(cr3, cg3, cb3, 1.f - ac3);
    __syncthreads();
    if (tid < 256) {
      int px = tid;
      float R = 0.f, Gc = 0.f, Bc = 0.f, T = 1.f;
#pragma unroll
      for (int s2 = 0; s2 < SEGN; ++s2) {
        float4 cv = comb[s2 * 256 + px];
        R += T * cv.x; Gc += T * cv.y; Bc += T * cv.z;
        T *= cv.w;
      }
      int p = bid * 256 + px;
      out[3 * p + 0] = R;
      out[3 * p + 1] = Gc;
      out[3 * p + 2] = Bc;
    }
  }
}

extern "C" void kernel_launch(void* const* d_in, const int* in_sizes, int n_in,
                              void* d_out, int out_size, void* d_ws, size_t ws_size,
                              hipStream_t stream) {
  const float* positions = (const float*)d_in[0];
  const float* scales    = (const float*)d_in[1];
  const float* rotations = (const float*)d_in[2];
  const float* colors    = (const float*)d_in[3];
  const float* opacity   = (const float*)d_in[4];
  const float* colors_sh = (const float*)d_in[5];
  const float* cam       = (const float*)d_in[6];
  const float* campos    = (const float*)d_in[7];
  int N = in_sizes[0] / 3;
  int shstride = in_sizes[5] / N;  // 48

  char* ws = (char*)d_ws;
  u32* keys    = (u32*)ws;                      // 4 MB
  u64* cand0   = (u64*)(ws + 4194304);          // 128 KB
  u64* cand    = (u64*)(ws + 4325376);          // 32 KB
  float* gauss = (float*)(ws + 4358144);        // 48 KB
  char* zr     = ws + 4407296;                  // zeroed region, 33280 B
  u32* hist1   = (u32*)zr;                      // 16 KB
  u32* hist2   = (u32*)(zr + 16384);            // 16 KB
  u32* state   = (u32*)(zr + 32768);            // 256 B
  u32* bar     = (u32*)(zr + 33024);            // 256 B
  float* out   = (float*)d_out;

  hipMemsetAsync(zr, 0, 33280, stream);

  void* args[] = {(void*)&positions, (void*)&scales, (void*)&rotations, (void*)&colors,
                  (void*)&opacity, (void*)&colors_sh, (void*)&cam, (void*)&campos,
                  (void*)&keys, (void*)&cand0, (void*)&cand, (void*)&gauss,
                  (void*)&hist1, (void*)&hist2, (void*)&state, (void*)&bar,
                  (void*)&out, (void*)&N, (void*)&shstride};
  hipLaunchCooperativeKernel((const void*)k_fused, dim3(NBLK), dim3(NTHR), args, 0, stream);
}

// Round 7
// 378.085 us; speedup vs baseline: 1.1907x; 1.1907x over previous
//
#include <hip/hip_runtime.h>
#include <stdint.h>

typedef uint32_t u32;
typedef uint64_t u64;

#define KREN 1000
#define CAND0_CAP 16384
#define CAND_CAP 4096
#define GSTRIDE 12
#define SEGN 16   // render: gaussian segments per pixel
#define P0_BLK 512
#define P1_BLK 512
#define P2_BLK 32
#define P3_BLK 1024

// monotonic float -> u32 key (larger key == larger float)
__device__ __forceinline__ u32 fkey(float f) {
  u32 b = __float_as_uint(f);
  return (b & 0x80000000u) ? ~b : (b | 0x80000000u);
}

// Block-redundant pick over a 4096-bin global hist, 256 threads (16 bins/thr):
// bin where descending cumulative count first reaches K. Deterministic.
__device__ __forceinline__ void pick_scan256(const u32* __restrict__ hist, u32 K,
                                             u32* lds, int* bin_out, u32* Krem_out) {
  int tid = threadIdx.x;
  u32 hv[16];
  u32 s = 0;
#pragma unroll
  for (int k = 0; k < 16; ++k) { hv[k] = hist[tid * 16 + k]; s += hv[k]; }
  lds[tid] = s;
  __syncthreads();
  for (int d = 1; d < 256; d <<= 1) {  // inclusive suffix sum
    u32 v = lds[tid] + ((tid + d < 256) ? lds[tid + d] : 0u);
    __syncthreads();
    lds[tid] = v;
    __syncthreads();
  }
  u32 inc = lds[tid];
  u32 above = (tid < 255) ? lds[tid + 1] : 0u;
  if (above < K && inc >= K) {  // unique crossing thread
    u32 cum = above;
    for (int k = 15; k >= 0; --k) {
      cum += hv[k];
      if (cum >= K) {
        lds[256] = (u32)(tid * 16 + k);
        lds[257] = K - (cum - hv[k]);
        break;
      }
    }
  }
  __syncthreads();
  *bin_out = (int)lds[256];
  *Krem_out = lds[257];
  __syncthreads();
}

// ---------- P0: depth keys + 12-bit hist (wave-aggregated LDS, sparse flush) ----------
__global__ __launch_bounds__(256) void k_p0(const float* __restrict__ pos,
                                            const float* __restrict__ cam,
                                            u32* __restrict__ keys,
                                            u32* __restrict__ hist1, int N) {
  __shared__ u32 hl[4096];
  int tid = threadIdx.x;
  int lane = tid & 63;
  for (int i = tid; i < 4096; i += 256) hl[i] = 0;
  __syncthreads();
  float c8 = cam[8], c9 = cam[9], c10 = cam[10], c11 = cam[11];
  for (int i = blockIdx.x * 256 + tid; i < N; i += P0_BLK * 256) {
    float x = pos[3 * i], y = pos[3 * i + 1], z = pos[3 * i + 2];
    u32 mk = fkey(c8 * x + c9 * y + c10 * z + c11);
    keys[i] = mk;
    u32 bin = mk >> 20;
    u64 todo = __ballot(true);  // keys concentrated: few distinct bins/wave
    while (todo) {
      int leader = __ffsll((unsigned long long)todo) - 1;
      u32 lbin = __shfl(bin, leader, 64);
      u64 same = __ballot(bin == lbin);
      if (lane == leader) atomicAdd(&hl[lbin], (u32)__popcll(same & todo));
      todo &= ~same;
    }
  }
  __syncthreads();
  for (int i = tid; i < 4096; i += 256) {
    u32 v = hl[i];
    if (v) atomicAdd(&hist1[i], v);
  }
}

// ---------- P1: pick bin1 (block-redundant) + level-2 hist + compact emit ----------
__global__ __launch_bounds__(256) void k_p1(const u32* __restrict__ keys,
                                            const u32* __restrict__ hist1,
                                            u32* __restrict__ hist2,
                                            u64* __restrict__ cand0,
                                            u32* __restrict__ state, int N) {
  __shared__ u32 hl[4096];
  __shared__ u32 sl[258];
  int tid = threadIdx.x;
  int lane = tid & 63;
  int bin1; u32 K1;
  pick_scan256(hist1, (u32)KREN, sl, &bin1, &K1);
  if (tid == 0) { state[4] = K1; state[5] = (u32)bin1; }  // same value from all blocks
  u32 pref = (u32)bin1;
  for (int i = tid; i < 4096; i += 256) hl[i] = 0;
  __syncthreads();
  for (int i = blockIdx.x * 256 + tid; i < N; i += P1_BLK * 256) {
    u32 k = keys[i];
    bool m = (k >> 20) == pref;
    if (m) atomicAdd(&hl[(k >> 8) & 4095u], 1u);
    u64 bm = __ballot(m);
    if (bm) {
      u32 base;
      int leader = __ffsll((unsigned long long)bm) - 1;
      if (lane == leader) base = atomicAdd(&state[1], (u32)__popcll(bm));
      base = __shfl(base, leader, 64);
      if (m) {
        u32 p = base + (u32)__popcll(bm & ((1ull << lane) - 1ull));
        if (p < CAND0_CAP) cand0[p] = (((u64)(~k)) << 32) | (u32)i;
      }
    }
  }
  __syncthreads();
  for (int i = tid; i < 4096; i += 256) {
    u32 v = hl[i];
    if (v) atomicAdd(&hist2[i], v);
  }
}

// ---------- P2: pick bin2 (block-redundant) + collect final candidates ----------
__global__ __launch_bounds__(256) void k_p2(const u64* __restrict__ cand0,
                                            const u32* __restrict__ hist2,
                                            u64* __restrict__ cand,
                                            u32* __restrict__ state) {
  __shared__ u32 sl[258];
  int tid = threadIdx.x;
  int lane = tid & 63;
  u32 K1 = state[4];
  u32 pref = state[5];
  int bin2; u32 K2;
  pick_scan256(hist2, K1, sl, &bin2, &K2);
  u32 Thi = ~((pref << 20) | (((u32)bin2) << 8));  // stored-key form: ~k <= Thi
  int M1 = (int)state[1];
  if (M1 > CAND0_CAP) M1 = CAND0_CAP;
  for (int i = blockIdx.x * 256 + tid; i < M1; i += P2_BLK * 256) {
    u64 e = cand0[i];
    bool m = (u32)(e >> 32) <= Thi;
    u64 bm = __ballot(m);
    if (bm) {
      u32 base;
      int leader = __ffsll((unsigned long long)bm) - 1;
      if (lane == leader) base = atomicAdd(&state[0], (u32)__popcll(bm));
      base = __shfl(base, leader, 64);
      if (m) {
        u32 p = base + (u32)__popcll(bm & ((1ull << lane) - 1ull));
        if (p < CAND_CAP) cand[p] = e;
      }
    }
  }
}

// ---------- P3: rank (wave-per-candidate) + preprocess top-K gaussians ----------
__global__ __launch_bounds__(256) void k_p3(
    const u64* __restrict__ cand, const u32* __restrict__ state,
    const float* __restrict__ pos, const float* __restrict__ scales,
    const float* __restrict__ rot, const float* __restrict__ colors,
    const float* __restrict__ opac, const float* __restrict__ csh,
    const float* __restrict__ cam, const float* __restrict__ campos,
    float* __restrict__ gauss, int shstride) {
  __shared__ u64 sc[CAND_CAP];  // 32 KB
  int tid = threadIdx.x, bid = blockIdx.x;
  int lane = tid & 63;
  int M = (int)state[0];
  if (M > CAND_CAP) M = CAND_CAP;
  if (bid * 4 >= M) return;
  for (int i = tid; i < M; i += 256) sc[i] = cand[i];
  __syncthreads();
  int c = bid * 4 + (tid >> 6);
  if (c >= M) return;
  u64 mine = sc[c];
  int cnt = 0;
  int JJ = (M + 63) >> 6;
  for (int jj = 0; jj < JJ; ++jj) {
    int j = lane + (jj << 6);
    if (j < M && sc[j] < mine) ++cnt;
  }
#pragma unroll
  for (int d = 32; d; d >>= 1) cnt += __shfl_xor(cnt, d, 64);
  int r = cnt;
  if (r >= KREN || lane != 0) return;
  int g = (int)(u32)(mine & 0xffffffffu);
  float x = pos[3 * g], y = pos[3 * g + 1], z = pos[3 * g + 2];
  float c0 = cam[0], c1 = cam[1], c2 = cam[2], c3 = cam[3];
  float c4 = cam[4], c5 = cam[5], c6 = cam[6], c7 = cam[7];
  float c8 = cam[8], c9 = cam[9], c10 = cam[10], c11 = cam[11];
  float dep = c8 * x + c9 * y + c10 * z + c11;
  float invd = 1.0f / (dep + 1e-7f);
  float p2x = (c0 * x + c1 * y + c2 * z + c3) * invd;
  float p2y = (c4 * x + c5 * y + c6 * z + c7) * invd;
  float qw = rot[4 * g], qx = rot[4 * g + 1], qy = rot[4 * g + 2], qz = rot[4 * g + 3];
  float qn = rsqrtf(qw * qw + qx * qx + qy * qy + qz * qz);
  qw *= qn; qx *= qn; qy *= qn; qz *= qn;
  float r00 = 1.f - 2.f * (qy * qy + qz * qz), r01 = 2.f * (qx * qy - qw * qz), r02 = 2.f * (qx * qz + qw * qy);
  float r10 = 2.f * (qx * qy + qw * qz), r11 = 1.f - 2.f * (qx * qx + qz * qz), r12 = 2.f * (qy * qz - qw * qx);
  float r20 = 2.f * (qx * qz - qw * qy), r21 = 2.f * (qy * qz + qw * qx), r22 = 1.f - 2.f * (qx * qx + qy * qy);
  float e0 = fmaxf(expf(scales[3 * g]), 1e-7f);
  float e1 = fmaxf(expf(scales[3 * g + 1]), 1e-7f);
  float e2 = fmaxf(expf(scales[3 * g + 2]), 1e-7f);
  float v0 = e0 * e0, v1 = e1 * e1, v2 = e2 * e2;
  float C00 = r00 * r00 * v0 + r01 * r01 * v1 + r02 * r02 * v2;
  float C01 = r00 * r10 * v0 + r01 * r11 * v1 + r02 * r12 * v2;
  float C02 = r00 * r20 * v0 + r01 * r21 * v1 + r02 * r22 * v2;
  float C11 = r10 * r10 * v0 + r11 * r11 * v1 + r12 * r12 * v2;
  float C12 = r10 * r20 * v0 + r11 * r21 * v1 + r12 * r22 * v2;
  float C22 = r20 * r20 * v0 + r21 * r21 * v1 + r22 * r22 * v2;
  float fx = c0, fy = c5;
  float jd = 1.0f / dep;
  float j0 = fx * jd, j2 = -fx * p2x * jd, j4 = fy * jd, j5 = -fy * p2y * jd;
  float u0x = j0 * C00 + j2 * C02;
  float u0y = j0 * C01 + j2 * C12;
  float u0z = j0 * C02 + j2 * C22;
  float u1y = j4 * C11 + j5 * C12;
  float u1z = j4 * C12 + j5 * C22;
  float a = u0x * j0 + u0z * j2 + 1e-6f;
  float b = u0y * j4 + u0z * j5;
  float d2 = u1y * j4 + u1z * j5 + 1e-6f;
  float det = a * d2 - b * b;
  float idet = 1.0f / det;
  const float L = 1.4426950408889634f;
  float Aq = -0.5f * L * d2 * idet;
  float Bq = L * b * idet;
  float Cq = -0.5f * L * a * idet;
  float vx = x - campos[0], vy = y - campos[1], vz = z - campos[2];
  float vn = rsqrtf(vx * vx + vy * vy + vz * vz);
  vx *= vn; vy *= vn; vz *= vn;
  float sh[9];
  sh[0] = 0.28209479177387814f;
  sh[1] = -0.48860251190291987f * vy;
  sh[2] = 0.48860251190291987f * vz;
  sh[3] = -0.48860251190291987f * vx;
  sh[4] = 1.0925484305920792f * vx * vy;
  sh[5] = -1.0925484305920792f * vy * vz;
  sh[6] = 0.31539156525252005f * (2.f * vz * vz - vx * vx - vy * vy);
  sh[7] = -1.0925484305920792f * vx * vz;
  sh[8] = 0.5462742152960396f * (vx * vx - vy * vy);
  float col[3];
  for (int c2 = 0; c2 < 3; ++c2) {
    float accv = colors[3 * g + c2];
    for (int k2 = 0; k2 < 9; ++k2) accv += sh[k2] * csh[(size_t)g * shstride + 3 * k2 + c2];
    col[c2] = 1.0f / (1.0f + __expf(-accv));
  }
  float op = 1.0f / (1.0f + __expf(-opac[g]));
  float* G = gauss + r * GSTRIDE;
  G[0] = p2x; G[1] = p2y; G[2] = Aq; G[3] = Bq; G[4] = Cq;
  G[5] = op;  G[6] = col[0]; G[7] = col[1]; G[8] = col[2];
  G[9] = 0.f; G[10] = 0.f; G[11] = 0.f;
}

// ---------- P4: render, 4 px/thread x 16 segments; comb aliases gs ----------
__global__ __launch_bounds__(1024) void k_p4(const float* __restrict__ gauss,
                                             float* __restrict__ out) {
  __shared__ u64 smem[8192];  // 64 KB
  int tid = threadIdx.x, bid = blockIdx.x;
  float* gs = (float*)smem;        // 12000 floats
  float4* g4s = (float4*)smem;
  const float4* g4 = (const float4*)gauss;
  for (int i = tid; i < 3000; i += 1024) g4s[i] = g4[i];
  __syncthreads();
  int grp = tid & 63;              // pixel group: px0 = grp*4
  int seg = tid >> 6;              // 0..15
  float pxf = (float)(grp * 4);
  float pyf = (float)bid;          // block = image row
  float cr0 = 0.f, cr1 = 0.f, cr2 = 0.f, cr3 = 0.f;
  float cg0 = 0.f, cg1 = 0.f, cg2 = 0.f, cg3 = 0.f;
  float cb0 = 0.f, cb1 = 0.f, cb2 = 0.f, cb3 = 0.f;
  float ac0 = 0.f, ac1 = 0.f, ac2 = 0.f, ac3 = 0.f;
  int gbeg = (seg * KREN) / SEGN, gend = ((seg + 1) * KREN) / SEGN;
  for (int k = gbeg; k < gend; ++k) {
    const float4* Gp = (const float4*)(gs + k * GSTRIDE);
    float4 g0 = Gp[0];
    float4 g1 = Gp[1];
    float g2x = gs[k * GSTRIDE + 8];
    float A = g0.z, B = g0.w, C = g1.x, op = g1.y;
    float dx = pxf - g0.x, dy = pyf - g0.y;
    float q0 = (A * dx + B * dy) * dx + C * dy * dy;
    float u = 2.f * A * dx + B * dy;
    float q1 = q0 + u + A;
    float q2 = q0 + 2.f * u + 4.f * A;
    float q3 = q0 + 3.f * u + 9.f * A;
    float e0 = op * exp2f(q0), e1 = op * exp2f(q1);
    float e2 = op * exp2f(q2), e3 = op * exp2f(q3);
    float w0 = (1.f - ac0) * e0, w1 = (1.f - ac1) * e1;
    float w2 = (1.f - ac2) * e2, w3 = (1.f - ac3) * e3;
    cr0 += w0 * g1.z; cg0 += w0 * g1.w; cb0 += w0 * g2x; ac0 += w0;
    cr1 += w1 * g1.z; cg1 += w1 * g1.w; cb1 += w1 * g2x; ac1 += w1;
    cr2 += w2 * g1.z; cg2 += w2 * g1.w; cb2 += w2 * g2x; ac2 += w2;
    cr3 += w3 * g1.z; cg3 += w3 * g1.w; cb3 += w3 * g2x; ac3 += w3;
  }
  __syncthreads();  // all waves done reading gs; comb reuses smem
  float4* comb = (float4*)smem;    // [seg][px]: 16*256 float4 = 64 KB
  int base = seg * 256 + grp * 4;
  comb[base + 0] = make_float4(cr0, cg0, cb0, 1.f - ac0);
  comb[base + 1] = make_float4(cr1, cg1, cb1, 1.f - ac1);
  comb[base + 2] = make_float4(cr2, cg2, cb2, 1.f - ac2);
  comb[base + 3] = make_float4(cr3, cg3, cb3, 1.f - ac3);
  __syncthreads();
  if (tid < 256) {
    int px = tid;
    float R = 0.f, Gc = 0.f, Bc = 0.f, T = 1.f;
#pragma unroll
    for (int s2 = 0; s2 < SEGN; ++s2) {
      float4 cv = comb[s2 * 256 + px];
      R += T * cv.x; Gc += T * cv.y; Bc += T * cv.z;
      T *= cv.w;
    }
    int p = bid * 256 + px;
    out[3 * p + 0] = R;
    out[3 * p + 1] = Gc;
    out[3 * p + 2] = Bc;
  }
}

extern "C" void kernel_launch(void* const* d_in, const int* in_sizes, int n_in,
                              void* d_out, int out_size, void* d_ws, size_t ws_size,
                              hipStream_t stream) {
  const float* positions = (const float*)d_in[0];
  const float* scales    = (const float*)d_in[1];
  const float* rotations = (const float*)d_in[2];
  const float* colors    = (const float*)d_in[3];
  const float* opacity   = (const float*)d_in[4];
  const float* colors_sh = (const float*)d_in[5];
  const float* cam       = (const float*)d_in[6];
  const float* campos    = (const float*)d_in[7];
  int N = in_sizes[0] / 3;
  int shstride = in_sizes[5] / N;  // 48

  char* ws = (char*)d_ws;
  u32* keys    = (u32*)ws;                      // 4 MB
  u64* cand0   = (u64*)(ws + 4194304);          // 128 KB
  u64* cand    = (u64*)(ws + 4325376);          // 32 KB
  float* gauss = (float*)(ws + 4358144);        // 48 KB
  char* zr     = ws + 4407296;                  // zeroed region, 33280 B
  u32* hist1   = (u32*)zr;                      // 16 KB
  u32* hist2   = (u32*)(zr + 16384);            // 16 KB
  u32* state   = (u32*)(zr + 32768);            // 256 B
  float* out   = (float*)d_out;

  hipMemsetAsync(zr, 0, 33280, stream);
  k_p0<<<P0_BLK, 256, 0, stream>>>(positions, cam, keys, hist1, N);
  k_p1<<<P1_BLK, 256, 0, stream>>>(keys, hist1, hist2, cand0, state, N);
  k_p2<<<P2_BLK, 256, 0, stream>>>(cand0, hist2, cand, state);
  k_p3<<<P3_BLK, 256, 0, stream>>>(cand, state, positions, scales, rotations,
                                   colors, opacity, colors_sh, cam, campos,
                                   gauss, shstride);
  k_p4<<<256, 1024, 0, stream>>>(gauss, out);
}

// Round 9
// 363.227 us; speedup vs baseline: 1.2394x; 1.0409x over previous
//
#include <hip/hip_runtime.h>
#include <stdint.h>

typedef uint32_t u32;
typedef uint64_t u64;

#define KREN 1000
#define CAND0_CAP 16384
#define GSTRIDE 12
#define STAGE_N 256     // gaussians staged in LDS for render (early-exit uses ~45)
#define P0_BLK 512
#define P1_BLK 512

// monotonic float -> u32 key (larger key == larger float)
__device__ __forceinline__ u32 fkey(float f) {
  u32 b = __float_as_uint(f);
  return (b & 0x80000000u) ? ~b : (b | 0x80000000u);
}

// Block-redundant pick over a 4096-bin global hist, 256 threads (16 bins/thr):
// returns bin where the descending cumulative count first reaches K.
__device__ __forceinline__ int pick_scan256(const u32* __restrict__ hist, u32 K,
                                            u32* lds) {
  int tid = threadIdx.x;
  u32 hv[16];
  u32 s = 0;
#pragma unroll
  for (int k = 0; k < 16; ++k) { hv[k] = hist[tid * 16 + k]; s += hv[k]; }
  lds[tid] = s;
  __syncthreads();
  for (int d = 1; d < 256; d <<= 1) {  // inclusive suffix sum
    u32 v = lds[tid] + ((tid + d < 256) ? lds[tid + d] : 0u);
    __syncthreads();
    lds[tid] = v;
    __syncthreads();
  }
  u32 inc = lds[tid];
  u32 above = (tid < 255) ? lds[tid + 1] : 0u;
  if (above < K && inc >= K) {  // unique crossing thread
    u32 cum = above;
    for (int k = 15; k >= 0; --k) {
      cum += hv[k];
      if (cum >= K) { lds[256] = (u32)(tid * 16 + k); break; }
    }
  }
  __syncthreads();
  int bin = (int)lds[256];
  __syncthreads();
  return bin;
}

// ---------- P0: depth keys (float4 loads, uint4 store) + 12-bit hist ----------
__global__ __launch_bounds__(256) void k_p0(const float* __restrict__ pos,
                                            const float* __restrict__ cam,
                                            u32* __restrict__ keys,
                                            u32* __restrict__ hist1, int N) {
  __shared__ u32 hl[4096];
  int tid = threadIdx.x;
  int lane = tid & 63;
  for (int i = tid; i < 4096; i += 256) hl[i] = 0;
  __syncthreads();
  float c8 = cam[8], c9 = cam[9], c10 = cam[10], c11 = cam[11];
  const float4* p4 = (const float4*)pos;
  uint4* k4 = (uint4*)keys;
  int NG = N >> 2;  // groups of 4 gaussians
  for (int g = blockIdx.x * 256 + tid; g < NG; g += P0_BLK * 256) {
    float4 v0 = p4[3 * g], v1 = p4[3 * g + 1], v2 = p4[3 * g + 2];
    u32 b0 = fkey(c8 * v0.x + c9 * v0.y + c10 * v0.z + c11);
    u32 b1 = fkey(c8 * v0.w + c9 * v1.x + c10 * v1.y + c11);
    u32 b2 = fkey(c8 * v1.z + c9 * v1.w + c10 * v2.x + c11);
    u32 b3 = fkey(c8 * v2.y + c9 * v2.z + c10 * v2.w + c11);
    k4[g] = make_uint4(b0, b1, b2, b3);
    u32 bins[4] = {b0 >> 20, b1 >> 20, b2 >> 20, b3 >> 20};
#pragma unroll
    for (int s = 0; s < 4; ++s) {  // wave-aggregated LDS hist (few distinct bins)
      u32 bin = bins[s];
      u64 todo = __ballot(true);
      while (todo) {
        int leader = __ffsll((unsigned long long)todo) - 1;
        u32 lbin = __shfl(bin, leader, 64);
        u64 same = __ballot(bin == lbin);
        if (lane == leader) atomicAdd(&hl[lbin], (u32)__popcll(same & todo));
        todo &= ~same;
      }
    }
  }
  __syncthreads();
  for (int i = tid; i < 4096; i += 256) {
    u32 v = hl[i];
    if (v) atomicAdd(&hist1[i], v);
  }
}

// ---------- P1: pick bin1 (block-redundant) + compact emit of key >= bin1<<20 ----------
__global__ __launch_bounds__(256) void k_p1(const u32* __restrict__ keys,
                                            const u32* __restrict__ hist1,
                                            u64* __restrict__ cand0,
                                            u32* __restrict__ state, int N) {
  __shared__ u32 sl[258];
  int tid = threadIdx.x;
  int lane = tid & 63;
  int bin1 = pick_scan256(hist1, (u32)KREN, sl);
  u32 T = ((u32)bin1) << 20;  // keep all keys >= T (count = suffix >= KREN)
  const uint4* k4 = (const uint4*)keys;
  int NG = N >> 2;
  for (int g = blockIdx.x * 256 + tid; g < NG; g += P1_BLK * 256) {
    uint4 kv = k4[g];
    u32 ka[4] = {kv.x, kv.y, kv.z, kv.w};
#pragma unroll
    for (int s = 0; s < 4; ++s) {
      bool m = ka[s] >= T;
      u64 bm = __ballot(m);
      if (bm) {
        u32 base;
        int leader = __ffsll((unsigned long long)bm) - 1;
        if (lane == leader) base = atomicAdd(&state[1], (u32)__popcll(bm));
        base = __shfl(base, leader, 64);
        if (m) {
          u32 p = base + (u32)__popcll(bm & ((1ull << lane) - 1ull));
          if (p < CAND0_CAP) cand0[p] = (((u64)(~ka[s])) << 32) | (u32)(4 * g + s);
        }
      }
    }
  }
}

// ---------- P3: rank (wave-per-candidate, global lane-strided) + prep ----------
__global__ __launch_bounds__(256) void k_p3(
    const u64* __restrict__ cand0, const u32* __restrict__ state,
    const float* __restrict__ pos, const float* __restrict__ scales,
    const float* __restrict__ rot, const float* __restrict__ colors,
    const float* __restrict__ opac, const float* __restrict__ csh,
    const float* __restrict__ cam, const float* __restrict__ campos,
    float* __restrict__ gauss, int shstride) {
  int tid = threadIdx.x, bid = blockIdx.x;
  int lane = tid & 63;
  int M = (int)state[1];
  if (M > CAND0_CAP) M = CAND0_CAP;
  int c = bid * 4 + (tid >> 6);
  if (c >= M) return;
  u64 mine = cand0[c];
  int cnt = 0;
  for (int j = lane; j < M; j += 64) cnt += (cand0[j] < mine) ? 1 : 0;
#pragma unroll
  for (int d = 32; d; d >>= 1) cnt += __shfl_xor(cnt, d, 64);
  int r = cnt;  // rank: depth desc, index asc (keys composite-unique)
  if (r >= KREN || lane != 0) return;
  int g = (int)(u32)(mine & 0xffffffffu);
  float x = pos[3 * g], y = pos[3 * g + 1], z = pos[3 * g + 2];
  float c0 = cam[0], c1 = cam[1], c2 = cam[2], c3 = cam[3];
  float c4 = cam[4], c5 = cam[5], c6 = cam[6], c7 = cam[7];
  float c8 = cam[8], c9 = cam[9], c10 = cam[10], c11 = cam[11];
  float dep = c8 * x + c9 * y + c10 * z + c11;
  float invd = 1.0f / (dep + 1e-7f);
  float p2x = (c0 * x + c1 * y + c2 * z + c3) * invd;
  float p2y = (c4 * x + c5 * y + c6 * z + c7) * invd;
  float qw = rot[4 * g], qx = rot[4 * g + 1], qy = rot[4 * g + 2], qz = rot[4 * g + 3];
  float qn = rsqrtf(qw * qw + qx * qx + qy * qy + qz * qz);
  qw *= qn; qx *= qn; qy *= qn; qz *= qn;
  float r00 = 1.f - 2.f * (qy * qy + qz * qz), r01 = 2.f * (qx * qy - qw * qz), r02 = 2.f * (qx * qz + qw * qy);
  float r10 = 2.f * (qx * qy + qw * qz), r11 = 1.f - 2.f * (qx * qx + qz * qz), r12 = 2.f * (qy * qz - qw * qx);
  float r20 = 2.f * (qx * qz - qw * qy), r21 = 2.f * (qy * qz + qw * qx), r22 = 1.f - 2.f * (qx * qx + qy * qy);
  float e0 = fmaxf(expf(scales[3 * g]), 1e-7f);
  float e1 = fmaxf(expf(scales[3 * g + 1]), 1e-7f);
  float e2 = fmaxf(expf(scales[3 * g + 2]), 1e-7f);
  float v0 = e0 * e0, v1 = e1 * e1, v2 = e2 * e2;
  float C00 = r00 * r00 * v0 + r01 * r01 * v1 + r02 * r02 * v2;
  float C01 = r00 * r10 * v0 + r01 * r11 * v1 + r02 * r12 * v2;
  float C02 = r00 * r20 * v0 + r01 * r21 * v1 + r02 * r22 * v2;
  float C11 = r10 * r10 * v0 + r11 * r11 * v1 + r12 * r12 * v2;
  float C12 = r10 * r20 * v0 + r11 * r21 * v1 + r12 * r22 * v2;
  float C22 = r20 * r20 * v0 + r21 * r21 * v1 + r22 * r22 * v2;
  float fx = c0, fy = c5;
  float jd = 1.0f / dep;
  float j0 = fx * jd, j2 = -fx * p2x * jd, j4 = fy * jd, j5 = -fy * p2y * jd;
  float u0x = j0 * C00 + j2 * C02;
  float u0y = j0 * C01 + j2 * C12;
  float u0z = j0 * C02 + j2 * C22;
  float u1y = j4 * C11 + j5 * C12;
  float u1z = j4 * C12 + j5 * C22;
  float a = u0x * j0 + u0z * j2 + 1e-6f;
  float b = u0y * j4 + u0z * j5;
  float d2 = u1y * j4 + u1z * j5 + 1e-6f;
  float det = a * d2 - b * b;
  float idet = 1.0f / det;
  const float L = 1.4426950408889634f;
  float Aq = -0.5f * L * d2 * idet;
  float Bq = L * b * idet;
  float Cq = -0.5f * L * a * idet;
  float vx = x - campos[0], vy = y - campos[1], vz = z - campos[2];
  float vn = rsqrtf(vx * vx + vy * vy + vz * vz);
  vx *= vn; vy *= vn; vz *= vn;
  float sh[9];
  sh[0] = 0.28209479177387814f;
  sh[1] = -0.48860251190291987f * vy;
  sh[2] = 0.48860251190291987f * vz;
  sh[3] = -0.48860251190291987f * vx;
  sh[4] = 1.0925484305920792f * vx * vy;
  sh[5] = -1.0925484305920792f * vy * vz;
  sh[6] = 0.31539156525252005f * (2.f * vz * vz - vx * vx - vy * vy);
  sh[7] = -1.0925484305920792f * vx * vz;
  sh[8] = 0.5462742152960396f * (vx * vx - vy * vy);
  float col[3];
  for (int c2 = 0; c2 < 3; ++c2) {
    float accv = colors[3 * g + c2];
    for (int k2 = 0; k2 < 9; ++k2) accv += sh[k2] * csh[(size_t)g * shstride + 3 * k2 + c2];
    col[c2] = 1.0f / (1.0f + __expf(-accv));
  }
  float op = 1.0f / (1.0f + __expf(-opac[g]));
  float* G = gauss + r * GSTRIDE;
  G[0] = p2x; G[1] = p2y; G[2] = Aq; G[3] = Bq; G[4] = Cq;
  G[5] = op;  G[6] = col[0]; G[7] = col[1]; G[8] = col[2];
  G[9] = 0.f; G[10] = 0.f; G[11] = 0.f;
}

// ---------- P4: render, 1 px/thread, wave-uniform early exit ----------
// Transmittance decays ~0.6^k (uniform opacity~0.52, huge cov2d) -> all pixels
// saturate (1-acc < 1e-7) within ~45 gaussians; truncation error <= 1e-7.
__global__ __launch_bounds__(256) void k_p4(const float* __restrict__ gauss,
                                            float* __restrict__ out) {
  __shared__ float gs[STAGE_N * GSTRIDE];  // 12 KB
  int tid = threadIdx.x, bid = blockIdx.x;
  const float4* g4 = (const float4*)gauss;
  float4* g4s = (float4*)gs;
  for (int i = tid; i < STAGE_N * 3; i += 256) g4s[i] = g4[i];
  __syncthreads();
  int p = bid * 256 + tid;
  float px = (float)(p & 255);
  float py = (float)(p >> 8);
  float cr = 0.f, cg = 0.f, cb = 0.f, acc = 0.f;
  int k = 0;
  for (; k < STAGE_N; ++k) {
    const float4* Gp = (const float4*)(gs + k * GSTRIDE);
    float4 g0 = Gp[0];
    float4 g1 = Gp[1];
    float g2x = gs[k * GSTRIDE + 8];
    float dx = px - g0.x, dy = py - g0.y;
    float sE = g0.z * dx * dx + g0.w * dx * dy + g1.x * dy * dy;
    float alpha = g1.y * exp2f(sE);
    float w = (1.0f - acc) * alpha;
    cr += w * g1.z; cg += w * g1.w; cb += w * g2x;
    acc += w;
    if (__all((1.0f - acc) < 1e-7f)) { k = KREN; break; }
  }
  for (; k < KREN; ++k) {  // cold fallback path (unstaged tail)
    const float4* Gp = (const float4*)(gauss + k * GSTRIDE);
    float4 g0 = Gp[0];
    float4 g1 = Gp[1];
    float g2x = gauss[k * GSTRIDE + 8];
    float dx = px - g0.x, dy = py - g0.y;
    float sE = g0.z * dx * dx + g0.w * dx * dy + g1.x * dy * dy;
    float alpha = g1.y * exp2f(sE);
    float w = (1.0f - acc) * alpha;
    cr += w * g1.z; cg += w * g1.w; cb += w * g2x;
    acc += w;
    if (__all((1.0f - acc) < 1e-7f)) break;
  }
  out[3 * p + 0] = cr;
  out[3 * p + 1] = cg;
  out[3 * p + 2] = cb;
}

extern "C" void kernel_launch(void* const* d_in, const int* in_sizes, int n_in,
                              void* d_out, int out_size, void* d_ws, size_t ws_size,
                              hipStream_t stream) {
  const float* positions = (const float*)d_in[0];
  const float* scales    = (const float*)d_in[1];
  const float* rotations = (const float*)d_in[2];
  const float* colors    = (const float*)d_in[3];
  const float* opacity   = (const float*)d_in[4];
  const float* colors_sh = (const float*)d_in[5];
  const float* cam       = (const float*)d_in[6];
  const float* campos    = (const float*)d_in[7];
  int N = in_sizes[0] / 3;
  int shstride = in_sizes[5] / N;  // 48

  char* ws = (char*)d_ws;
  u32* keys    = (u32*)ws;                      // 4 MB
  u64* cand0   = (u64*)(ws + 4194304);          // 128 KB
  float* gauss = (float*)(ws + 4325376);        // 48 KB
  char* zr     = ws + 4374528;                  // zeroed: hist1 16 KB + state 256 B
  u32* hist1   = (u32*)zr;
  u32* state   = (u32*)(zr + 16384);
  float* out   = (float*)d_out;

  hipMemsetAsync(zr, 0, 16640, stream);
  k_p0<<<P0_BLK, 256, 0, stream>>>(positions, cam, keys, hist1, N);
  k_p1<<<P1_BLK, 256, 0, stream>>>(keys, hist1, cand0, state, N);
  k_p3<<<CAND0_CAP / 4, 256, 0, stream>>>(cand0, state, positions, scales, rotations,
                                          colors, opacity, colors_sh, cam, campos,
                                          gauss, shstride);
  k_p4<<<256, 256, 0, stream>>>(gauss, out);
}